// Round 1
// baseline (898.020 us; speedup 1.0000x reference)
//
#include <hip/hip_runtime.h>

namespace {

constexpr int NN = 65536;      // nodes
constexpr int NE = 1 << 20;    // edges
constexpr int HD = 64;         // hidden
constexpr int H2 = 128;        // 2*hidden
constexpr int NL = 4;          // layers
constexpr float GEPS = 1e-7f;
constexpr float LNEPS = 1e-5f;

// ---------- encoders: h[N,64], eenc[65536,64] ----------
__global__ __launch_bounds__(256) void k_encode(
    const float* __restrict__ x, const float* __restrict__ ea,
    const float* __restrict__ nW, const float* __restrict__ nb,
    const float* __restrict__ eW, const float* __restrict__ eb,
    float* __restrict__ h, float* __restrict__ eenc) {
  int g = blockIdx.x * 256 + threadIdx.x;  // 0 .. 4M-1 (both arrays 65536*64)
  int c = g & 63;
  int i = g >> 6;
  h[g] = x[i] * nW[c] + nb[c];
  eenc[g] = ea[i] * eW[c] + eb[c];   // only edge_attr[0:65536] is used (tile structure)
}

// ---------- counting sort by dst ----------
__global__ __launch_bounds__(256) void k_count(const int* __restrict__ dst,
                                               int* __restrict__ counts) {
  int e = blockIdx.x * 256 + threadIdx.x;
  atomicAdd(&counts[dst[e]], 1);
}

__global__ __launch_bounds__(256) void k_scan1(const int* __restrict__ counts,
                                               int* __restrict__ offsets,
                                               int* __restrict__ blockTot) {
  __shared__ int s[256];
  int t = threadIdx.x;
  int g = blockIdx.x * 256 + t;
  int v = counts[g];
  s[t] = v;
  __syncthreads();
  for (int d = 1; d < 256; d <<= 1) {
    int val = (t >= d) ? s[t - d] : 0;
    __syncthreads();
    s[t] += val;
    __syncthreads();
  }
  offsets[g] = s[t] - v;              // block-local exclusive
  if (t == 255) blockTot[blockIdx.x] = s[255];
}

__global__ __launch_bounds__(256) void k_scan2(int* __restrict__ blockTot) {
  __shared__ int s[256];
  int t = threadIdx.x;
  int v = blockTot[t];
  s[t] = v;
  __syncthreads();
  for (int d = 1; d < 256; d <<= 1) {
    int val = (t >= d) ? s[t - d] : 0;
    __syncthreads();
    s[t] += val;
    __syncthreads();
  }
  blockTot[t] = s[t] - v;             // exclusive block bases
}

__global__ __launch_bounds__(256) void k_scan3(const int* __restrict__ blockTot,
                                               int* __restrict__ offsets,
                                               int* __restrict__ cursor) {
  int g = blockIdx.x * 256 + threadIdx.x;
  int v = offsets[g] + blockTot[blockIdx.x];
  offsets[g] = v;
  cursor[g] = v;
  if (g == 0) offsets[NN] = NE;
}

__global__ __launch_bounds__(256) void k_scatter(const int* __restrict__ src,
                                                 const int* __restrict__ dst,
                                                 int* __restrict__ cursor,
                                                 int* __restrict__ ssrc,
                                                 unsigned short* __restrict__ selo) {
  int e = blockIdx.x * 256 + threadIdx.x;
  int d = dst[e];
  int pos = atomicAdd(&cursor[d], 1);
  ssrc[pos] = src[e];
  selo[pos] = (unsigned short)(e & 65535);
}

// ---------- hin = relu(LN(h; g,b)) over 64 channels ----------
__global__ __launch_bounds__(256) void k_lnrelu(const float* __restrict__ h,
                                                float* __restrict__ hin,
                                                const float* __restrict__ gg,
                                                const float* __restrict__ bb) {
  int lane = threadIdx.x & 63;
  int node = blockIdx.x * 4 + (threadIdx.x >> 6);
  float v = h[node * 64 + lane];
  float s = v, q = v * v;
#pragma unroll
  for (int m = 1; m < 64; m <<= 1) {
    s += __shfl_xor(s, m);
    q += __shfl_xor(q, m);
  }
  float mu = s * (1.0f / 64.0f);
  float var = q * (1.0f / 64.0f) - mu * mu;
  float r = rsqrtf(var + LNEPS);
  float o = (v - mu) * r * gg[lane] + bb[lane];
  hin[node * 64 + lane] = fmaxf(o, 0.0f);
}

// ---------- per-dst online-softmax aggregation; z = agg + hin ----------
__global__ __launch_bounds__(256) void k_agg(const float* __restrict__ hin,
                                             const float* __restrict__ eenc,
                                             const int* __restrict__ offsets,
                                             const int* __restrict__ ssrc,
                                             const unsigned short* __restrict__ selo,
                                             const float* __restrict__ conv_t, int layer,
                                             float* __restrict__ zbuf) {
  int lane = threadIdx.x & 63;
  int d = blockIdx.x * 4 + (threadIdx.x >> 6);
  float t = conv_t[layer];
  int off = __builtin_amdgcn_readfirstlane(offsets[d]);
  int end = __builtin_amdgcn_readfirstlane(offsets[d + 1]);
  float mx = -INFINITY, den = 0.0f, num = 0.0f;
  for (int k = off; k < end; ++k) {
    int s = __builtin_amdgcn_readfirstlane(ssrc[k]);
    int j = __builtin_amdgcn_readfirstlane((int)selo[k]);
    float m = fmaxf(hin[s * 64 + lane] + eenc[j * 64 + lane], 0.0f) + GEPS;
    float lg = m * t;
    float nm = fmaxf(mx, lg);
    float sc = __expf(mx - nm);     // exp(-inf)=0 on first iter
    float ex = __expf(lg - nm);
    den = den * sc + ex;
    num = num * sc + m * ex;
    mx = nm;
  }
  float agg = num / fmaxf(den, 1e-16f);
  zbuf[d * 64 + lane] = agg + hin[d * 64 + lane];
}

// ---------- fused node MLP: z->W1->LN->relu->W2 (+residual) ----------
__global__ __launch_bounds__(256) void k_mlp(const float* __restrict__ zbuf,
                                             float* __restrict__ h,
                                             const float* __restrict__ W1,
                                             const float* __restrict__ b1,
                                             const float* __restrict__ g1,
                                             const float* __restrict__ bt1,
                                             const float* __restrict__ W2,
                                             const float* __restrict__ b2,
                                             int layer0) {
  __shared__ __align__(16) float zt[32][68];
  __shared__ __align__(16) float wbuf[8704];    // phase1: [64][132]; phase2: [128][68]
  __shared__ __align__(16) float y1[32][132];
  int tid = threadIdx.x;
  int n0 = blockIdx.x * 32;

  for (int i = tid; i < 32 * 64; i += 256) zt[i >> 6][i & 63] = zbuf[n0 * 64 + i];
  for (int i = tid; i < H2 * 64; i += 256) {
    int j = i >> 6, k = i & 63;
    wbuf[k * 132 + j] = W1[i];                  // W1[j][k] -> w1t[k][j]
  }
  __syncthreads();

  int ng = (tid >> 4) * 2;     // node pair
  int cg = (tid & 15) * 8;     // 8 output cols of 128
  float acc[2][8];
#pragma unroll
  for (int i = 0; i < 2; ++i)
#pragma unroll
    for (int j = 0; j < 8; ++j) acc[i][j] = 0.0f;

#pragma unroll 4
  for (int k = 0; k < 64; ++k) {
    float z0 = zt[ng][k];
    float z1 = zt[ng + 1][k];
    const float4 wa = *reinterpret_cast<const float4*>(&wbuf[k * 132 + cg]);
    const float4 wb = *reinterpret_cast<const float4*>(&wbuf[k * 132 + cg + 4]);
    acc[0][0] += z0 * wa.x; acc[0][1] += z0 * wa.y; acc[0][2] += z0 * wa.z; acc[0][3] += z0 * wa.w;
    acc[0][4] += z0 * wb.x; acc[0][5] += z0 * wb.y; acc[0][6] += z0 * wb.z; acc[0][7] += z0 * wb.w;
    acc[1][0] += z1 * wa.x; acc[1][1] += z1 * wa.y; acc[1][2] += z1 * wa.z; acc[1][3] += z1 * wa.w;
    acc[1][4] += z1 * wb.x; acc[1][5] += z1 * wb.y; acc[1][6] += z1 * wb.z; acc[1][7] += z1 * wb.w;
  }
#pragma unroll
  for (int i = 0; i < 2; ++i)
#pragma unroll
    for (int j = 0; j < 8; ++j) y1[ng + i][cg + j] = acc[i][j] + b1[cg + j];
  __syncthreads();

  // LN + relu over 128 cols; 8 threads per node
  {
    int n = tid >> 3, j0 = (tid & 7) * 16;
    float s = 0.0f, q = 0.0f;
#pragma unroll
    for (int j = 0; j < 16; ++j) {
      float v = y1[n][j0 + j];
      s += v; q += v * v;
    }
#pragma unroll
    for (int m = 1; m < 8; m <<= 1) {
      s += __shfl_xor(s, m);
      q += __shfl_xor(q, m);
    }
    float mu = s * (1.0f / 128.0f);
    float var = q * (1.0f / 128.0f) - mu * mu;
    float r = rsqrtf(var + LNEPS);
#pragma unroll
    for (int j = 0; j < 16; ++j) {
      float v = y1[n][j0 + j];
      float o = (v - mu) * r * g1[j0 + j] + bt1[j0 + j];
      y1[n][j0 + j] = fmaxf(o, 0.0f);
    }
  }
  // load W2 transposed (overwrites w1t; GEMM1 finished before previous barrier)
  for (int i = tid; i < 64 * H2; i += 256) {
    int c = i >> 7, j = i & 127;
    wbuf[j * 68 + c] = W2[i];                   // W2[c][j] -> w2t[j][c]
  }
  __syncthreads();

  int cg2 = (tid & 15) * 4;   // 4 output cols of 64
  float acc2[2][4] = {{0, 0, 0, 0}, {0, 0, 0, 0}};
#pragma unroll 4
  for (int j = 0; j < H2; ++j) {
    float r0 = y1[ng][j];
    float r1 = y1[ng + 1][j];
    const float4 w = *reinterpret_cast<const float4*>(&wbuf[j * 68 + cg2]);
    acc2[0][0] += r0 * w.x; acc2[0][1] += r0 * w.y; acc2[0][2] += r0 * w.z; acc2[0][3] += r0 * w.w;
    acc2[1][0] += r1 * w.x; acc2[1][1] += r1 * w.y; acc2[1][2] += r1 * w.z; acc2[1][3] += r1 * w.w;
  }
#pragma unroll
  for (int i = 0; i < 2; ++i)
#pragma unroll
    for (int c = 0; c < 4; ++c) {
      int g = (n0 + ng + i) * 64 + cg2 + c;
      float o = acc2[i][c] + b2[cg2 + c];
      h[g] = layer0 ? o : (h[g] + o);
    }
}

// ---------- readout: relu(LN(h; ln_g[0], ln_b[0])) . lin_W, per sample ----------
__global__ __launch_bounds__(256) void k_readout1(const float* __restrict__ h,
                                                  const float* __restrict__ gg,
                                                  const float* __restrict__ bb,
                                                  const float* __restrict__ linW,
                                                  float* __restrict__ partials) {
  int lane = threadIdx.x & 63;
  int w = threadIdx.x >> 6;
  int node = blockIdx.x * 4 + w;
  float v = h[node * 64 + lane];
  float s = v, q = v * v;
#pragma unroll
  for (int m = 1; m < 64; m <<= 1) {
    s += __shfl_xor(s, m);
    q += __shfl_xor(q, m);
  }
  float mu = s * (1.0f / 64.0f);
  float var = q * (1.0f / 64.0f) - mu * mu;
  float r = rsqrtf(var + LNEPS);
  float hf = fmaxf((v - mu) * r * gg[lane] + bb[lane], 0.0f);
  float p = hf * linW[(node & 4095) * 64 + lane];
#pragma unroll
  for (int m = 1; m < 64; m <<= 1) p += __shfl_xor(p, m);
  __shared__ float sp[4];
  if (lane == 0) sp[w] = p;
  __syncthreads();
  if (threadIdx.x == 0) partials[blockIdx.x] = sp[0] + sp[1] + sp[2] + sp[3];
}

__global__ __launch_bounds__(256) void k_readout2(const float* __restrict__ partials,
                                                  const float* __restrict__ linb,
                                                  float* __restrict__ out) {
  __shared__ float s[256];
  int b = blockIdx.x, t = threadIdx.x;
  float acc = 0.0f;
  for (int i = t; i < 1024; i += 256) acc += partials[b * 1024 + i];
  s[t] = acc;
  __syncthreads();
  for (int d = 128; d > 0; d >>= 1) {
    if (t < d) s[t] += s[t + d];
    __syncthreads();
  }
  if (t == 0) out[b] = s[0] + linb[0];
}

}  // namespace

extern "C" void kernel_launch(void* const* d_in, const int* in_sizes, int n_in,
                              void* d_out, int out_size, void* d_ws, size_t ws_size,
                              hipStream_t stream) {
  const float* x = (const float*)d_in[0];
  const int* ei = (const int*)d_in[1];
  const float* ea = (const float*)d_in[2];
  const float* nW = (const float*)d_in[5];
  const float* nb = (const float*)d_in[6];
  const float* eW = (const float*)d_in[7];
  const float* eb = (const float*)d_in[8];
  const float* W1 = (const float*)d_in[9];
  const float* b1 = (const float*)d_in[10];
  const float* g1 = (const float*)d_in[11];
  const float* bt1 = (const float*)d_in[12];
  const float* W2 = (const float*)d_in[13];
  const float* b2 = (const float*)d_in[14];
  const float* ct = (const float*)d_in[15];
  const float* lng = (const float*)d_in[16];
  const float* lnb = (const float*)d_in[17];
  const float* linW = (const float*)d_in[18];
  const float* linb = (const float*)d_in[19];
  float* out = (float*)d_out;

  const int* src = ei;
  const int* dst = ei + NE;

  // workspace carve
  char* p = (char*)d_ws;
  auto alloc = [&](size_t bytes) {
    char* r = p;
    p += (bytes + 255) & ~size_t(255);
    return r;
  };
  float* h = (float*)alloc(size_t(NN) * 64 * 4);
  float* hin = (float*)alloc(size_t(NN) * 64 * 4);
  float* zbuf = (float*)alloc(size_t(NN) * 64 * 4);
  float* eenc = (float*)alloc(size_t(65536) * 64 * 4);
  int* ssrc = (int*)alloc(size_t(NE) * 4);
  unsigned short* selo = (unsigned short*)alloc(size_t(NE) * 2);
  int* counts = (int*)alloc(size_t(NN) * 4);
  int* offsets = (int*)alloc(size_t(NN + 1) * 4);
  int* blockTot = (int*)alloc(256 * 4);
  int* cursor = (int*)alloc(size_t(NN) * 4);
  float* partials = (float*)alloc(16384 * 4);

  k_encode<<<16384, 256, 0, stream>>>(x, ea, nW, nb, eW, eb, h, eenc);

  hipMemsetAsync(counts, 0, size_t(NN) * 4, stream);
  k_count<<<NE / 256, 256, 0, stream>>>(dst, counts);
  k_scan1<<<256, 256, 0, stream>>>(counts, offsets, blockTot);
  k_scan2<<<1, 256, 0, stream>>>(blockTot);
  k_scan3<<<256, 256, 0, stream>>>(blockTot, offsets, cursor);
  k_scatter<<<NE / 256, 256, 0, stream>>>(src, dst, cursor, ssrc, selo);

  for (int l = 0; l < NL; ++l) {
    const float* hi;
    if (l == 0) {
      hi = h;
    } else {
      k_lnrelu<<<NN / 4, 256, 0, stream>>>(h, hin, lng + l * 64, lnb + l * 64);
      hi = hin;
    }
    k_agg<<<NN / 4, 256, 0, stream>>>(hi, eenc, offsets, ssrc, selo, ct, l, zbuf);
    k_mlp<<<NN / 32, 256, 0, stream>>>(zbuf, h,
                                       W1 + l * H2 * 64, b1 + l * H2,
                                       g1 + l * H2, bt1 + l * H2,
                                       W2 + l * 64 * H2, b2 + l * 64,
                                       l == 0 ? 1 : 0);
  }

  k_readout1<<<NN / 4, 256, 0, stream>>>(h, lng, lnb, linW, partials);
  k_readout2<<<16, 256, 0, stream>>>(partials, linb, out);
}

// Round 2
// 740.176 us; speedup vs baseline: 1.2133x; 1.2133x over previous
//
#include <hip/hip_runtime.h>

namespace {

constexpr int NN = 65536;      // nodes
constexpr int NE = 1 << 20;    // edges
constexpr int H2 = 128;        // 2*hidden
constexpr int NL = 4;          // layers
constexpr float GEPS = 1e-7f;
constexpr float LNEPS = 1e-5f;

// ---------- encoders: h[N,64], eenc[65536,64] ----------
__global__ __launch_bounds__(256) void k_encode(
    const float* __restrict__ x, const float* __restrict__ ea,
    const float* __restrict__ nW, const float* __restrict__ nb,
    const float* __restrict__ eW, const float* __restrict__ eb,
    float* __restrict__ h, float* __restrict__ eenc) {
  int g = blockIdx.x * 256 + threadIdx.x;  // 0 .. 4M-1 (both arrays 65536*64)
  int c = g & 63;
  int i = g >> 6;
  h[g] = x[i] * nW[c] + nb[c];
  eenc[g] = ea[i] * eW[c] + eb[c];   // only edge_attr[0:65536] is used (tile structure)
}

// ---------- counting sort by dst ----------
__global__ __launch_bounds__(256) void k_count(const int* __restrict__ dst,
                                               int* __restrict__ counts) {
  int e = blockIdx.x * 256 + threadIdx.x;
  atomicAdd(&counts[dst[e]], 1);
}

__global__ __launch_bounds__(256) void k_scan1(const int* __restrict__ counts,
                                               int* __restrict__ offsets,
                                               int* __restrict__ blockTot) {
  __shared__ int s[256];
  int t = threadIdx.x;
  int g = blockIdx.x * 256 + t;
  int v = counts[g];
  s[t] = v;
  __syncthreads();
  for (int d = 1; d < 256; d <<= 1) {
    int val = (t >= d) ? s[t - d] : 0;
    __syncthreads();
    s[t] += val;
    __syncthreads();
  }
  offsets[g] = s[t] - v;              // block-local exclusive
  if (t == 255) blockTot[blockIdx.x] = s[255];
}

__global__ __launch_bounds__(256) void k_scan2(int* __restrict__ blockTot) {
  __shared__ int s[256];
  int t = threadIdx.x;
  int v = blockTot[t];
  s[t] = v;
  __syncthreads();
  for (int d = 1; d < 256; d <<= 1) {
    int val = (t >= d) ? s[t - d] : 0;
    __syncthreads();
    s[t] += val;
    __syncthreads();
  }
  blockTot[t] = s[t] - v;             // exclusive block bases
}

__global__ __launch_bounds__(256) void k_scan3(const int* __restrict__ blockTot,
                                               int* __restrict__ offsets,
                                               int* __restrict__ cursor) {
  int g = blockIdx.x * 256 + threadIdx.x;
  int v = offsets[g] + blockTot[blockIdx.x];
  offsets[g] = v;
  cursor[g] = v;
  if (g == 0) offsets[NN] = NE;
}

// pack (src, eid&65535) into one dword — both fit in 16 bits (NN=65536, E/B=65536)
__global__ __launch_bounds__(256) void k_scatter(const int* __restrict__ src,
                                                 const int* __restrict__ dst,
                                                 int* __restrict__ cursor,
                                                 unsigned* __restrict__ epack) {
  int e = blockIdx.x * 256 + threadIdx.x;
  int d = dst[e];
  int pos = atomicAdd(&cursor[d], 1);
  epack[pos] = ((unsigned)src[e] << 16) | (unsigned)(e & 65535);
}

// ---------- per-dst online-softmax aggregation; z = agg + hi ----------
__global__ __launch_bounds__(256) void k_agg(const float* __restrict__ hin,
                                             const float* __restrict__ eenc,
                                             const int* __restrict__ offsets,
                                             const unsigned* __restrict__ epack,
                                             const float* __restrict__ conv_t, int layer,
                                             float* __restrict__ zbuf) {
  int lane = threadIdx.x & 63;
  int d = blockIdx.x * 4 + (threadIdx.x >> 6);
  float t = conv_t[layer];
  int off = __builtin_amdgcn_readfirstlane(offsets[d]);
  int end = __builtin_amdgcn_readfirstlane(offsets[d + 1]);
  float hself = hin[d * 64 + lane];

  float mxA = -INFINITY, denA = 0.f, numA = 0.f;
  float mxB = -INFINITY, denB = 0.f, numB = 0.f;

  auto chunk4 = [&](int k, float& mx, float& den, float& num) {
    unsigned p0 = epack[k], p1 = epack[k + 1], p2 = epack[k + 2], p3 = epack[k + 3];
    float g0 = hin[(p0 >> 16) * 64 + lane] + eenc[(p0 & 65535u) * 64 + lane];
    float g1 = hin[(p1 >> 16) * 64 + lane] + eenc[(p1 & 65535u) * 64 + lane];
    float g2 = hin[(p2 >> 16) * 64 + lane] + eenc[(p2 & 65535u) * 64 + lane];
    float g3 = hin[(p3 >> 16) * 64 + lane] + eenc[(p3 & 65535u) * 64 + lane];
    float m0 = fmaxf(g0, 0.f) + GEPS, m1 = fmaxf(g1, 0.f) + GEPS;
    float m2 = fmaxf(g2, 0.f) + GEPS, m3 = fmaxf(g3, 0.f) + GEPS;
    float l0 = m0 * t, l1 = m1 * t, l2 = m2 * t, l3 = m3 * t;
    float nm = fmaxf(fmaxf(fmaxf(l0, l1), fmaxf(l2, l3)), mx);
    float sc = __expf(mx - nm);                 // exp(-inf - finite) = 0 on first chunk
    float e0 = __expf(l0 - nm), e1 = __expf(l1 - nm);
    float e2 = __expf(l2 - nm), e3 = __expf(l3 - nm);
    den = den * sc + ((e0 + e1) + (e2 + e3));
    num = num * sc + ((m0 * e0 + m1 * e1) + (m2 * e2 + m3 * e3));
    mx = nm;
  };

  int k = off;
  for (; k + 8 <= end; k += 8) {   // two independent chains -> 16 gathers in flight
    chunk4(k, mxA, denA, numA);
    chunk4(k + 4, mxB, denB, numB);
  }
  if (k + 4 <= end) { chunk4(k, mxA, denA, numA); k += 4; }
  for (; k < end; ++k) {
    unsigned p = epack[k];
    float g = hin[(p >> 16) * 64 + lane] + eenc[(p & 65535u) * 64 + lane];
    float m = fmaxf(g, 0.f) + GEPS;
    float lg = m * t;
    float nm = fmaxf(mxA, lg);
    float sc = __expf(mxA - nm), ex = __expf(lg - nm);
    denA = denA * sc + ex;
    numA = numA * sc + m * ex;
    mxA = nm;
  }
  // merge chains (guard the -inf - -inf = nan case for empty/short buckets)
  float mxm = fmaxf(mxA, mxB);
  float scA = (mxA == mxm) ? 1.f : __expf(mxA - mxm);
  float scB = (mxB == mxm) ? 1.f : __expf(mxB - mxm);
  float den = denA * scA + denB * scB;
  float num = numA * scA + numB * scB;
  float agg = num / fmaxf(den, 1e-16f);
  zbuf[d * 64 + lane] = agg + hself;
}

// ---------- fused node MLP: z->W1->LN->relu->W2 (+residual) + next-layer LN/relu ----------
// mode 0: layer 0  (h = out;        write hin for next layer)
// mode 1: mid      (h += out;       write hin for next layer)
// mode 2: last     (hv = h + out;   readout partials, no h write)
__global__ __launch_bounds__(256) void k_mlp(const float* __restrict__ zbuf,
                                             float* __restrict__ h,
                                             float* __restrict__ hin_out,
                                             const float* __restrict__ W1,
                                             const float* __restrict__ b1,
                                             const float* __restrict__ g1,
                                             const float* __restrict__ bt1,
                                             const float* __restrict__ W2,
                                             const float* __restrict__ b2,
                                             const float* __restrict__ gnext,
                                             const float* __restrict__ bnext,
                                             const float* __restrict__ linW,
                                             float* __restrict__ partials,
                                             int mode) {
  __shared__ __align__(16) float zt[32][68];
  __shared__ __align__(16) float wbuf[8704];    // phase1: [64][132]; phase2: [128][68]
  __shared__ __align__(16) float y1[32][132];
  int tid = threadIdx.x;
  int n0 = blockIdx.x * 32;

  for (int i = tid; i < 32 * 64; i += 256) zt[i >> 6][i & 63] = zbuf[n0 * 64 + i];
  for (int i = tid; i < H2 * 64; i += 256) {
    int j = i >> 6, k = i & 63;
    wbuf[k * 132 + j] = W1[i];                  // W1[j][k] -> w1t[k][j]
  }
  __syncthreads();

  int ng = (tid >> 4) * 2;     // node pair
  int cg = (tid & 15) * 8;     // 8 output cols of 128
  float acc[2][8];
#pragma unroll
  for (int i = 0; i < 2; ++i)
#pragma unroll
    for (int j = 0; j < 8; ++j) acc[i][j] = 0.0f;

#pragma unroll 4
  for (int k = 0; k < 64; ++k) {
    float z0 = zt[ng][k];
    float z1 = zt[ng + 1][k];
    const float4 wa = *reinterpret_cast<const float4*>(&wbuf[k * 132 + cg]);
    const float4 wb = *reinterpret_cast<const float4*>(&wbuf[k * 132 + cg + 4]);
    acc[0][0] += z0 * wa.x; acc[0][1] += z0 * wa.y; acc[0][2] += z0 * wa.z; acc[0][3] += z0 * wa.w;
    acc[0][4] += z0 * wb.x; acc[0][5] += z0 * wb.y; acc[0][6] += z0 * wb.z; acc[0][7] += z0 * wb.w;
    acc[1][0] += z1 * wa.x; acc[1][1] += z1 * wa.y; acc[1][2] += z1 * wa.z; acc[1][3] += z1 * wa.w;
    acc[1][4] += z1 * wb.x; acc[1][5] += z1 * wb.y; acc[1][6] += z1 * wb.z; acc[1][7] += z1 * wb.w;
  }
#pragma unroll
  for (int i = 0; i < 2; ++i)
#pragma unroll
    for (int j = 0; j < 8; ++j) y1[ng + i][cg + j] = acc[i][j] + b1[cg + j];
  __syncthreads();

  // LN + relu over 128 cols; 8 threads per node
  {
    int n = tid >> 3, j0 = (tid & 7) * 16;
    float s = 0.0f, q = 0.0f;
#pragma unroll
    for (int j = 0; j < 16; ++j) {
      float v = y1[n][j0 + j];
      s += v; q += v * v;
    }
#pragma unroll
    for (int m = 1; m < 8; m <<= 1) {
      s += __shfl_xor(s, m);
      q += __shfl_xor(q, m);
    }
    float mu = s * (1.0f / 128.0f);
    float var = q * (1.0f / 128.0f) - mu * mu;
    float r = rsqrtf(var + LNEPS);
#pragma unroll
    for (int j = 0; j < 16; ++j) {
      float v = y1[n][j0 + j];
      float o = (v - mu) * r * g1[j0 + j] + bt1[j0 + j];
      y1[n][j0 + j] = fmaxf(o, 0.0f);
    }
  }
  // load W2 transposed (overwrites w1t; GEMM1 finished before previous barrier)
  for (int i = tid; i < 64 * H2; i += 256) {
    int c = i >> 7, j = i & 127;
    wbuf[j * 68 + c] = W2[i];                   // W2[c][j] -> w2t[j][c]
  }
  __syncthreads();

  int cg2 = (tid & 15) * 4;   // 4 output cols of 64
  float acc2[2][4] = {{0, 0, 0, 0}, {0, 0, 0, 0}};
#pragma unroll 4
  for (int j = 0; j < H2; ++j) {
    float r0 = y1[ng][j];
    float r1 = y1[ng + 1][j];
    const float4 w = *reinterpret_cast<const float4*>(&wbuf[j * 68 + cg2]);
    acc2[0][0] += r0 * w.x; acc2[0][1] += r0 * w.y; acc2[0][2] += r0 * w.z; acc2[0][3] += r0 * w.w;
    acc2[1][0] += r1 * w.x; acc2[1][1] += r1 * w.y; acc2[1][2] += r1 * w.z; acc2[1][3] += r1 * w.w;
  }
  // stash GEMM2 result in zt (free since the post-GEMM1 barrier)
#pragma unroll
  for (int i = 0; i < 2; ++i)
#pragma unroll
    for (int c = 0; c < 4; ++c) zt[ng + i][cg2 + c] = acc2[i][c];
  __syncthreads();

  // fused epilogue: residual + LN(gnext,bnext) + relu; write hin or readout partials
  int lane = tid & 63, w = tid >> 6;
  float b2v = b2[lane];
  float gnv = gnext[lane];
  float bnv = bnext[lane];
#pragma unroll
  for (int it = 0; it < 8; ++it) {
    int n = w * 8 + it;
    int gn = n0 + n;
    float o = zt[n][lane] + b2v;
    float hv = (mode == 0) ? o : (h[gn * 64 + lane] + o);
    if (mode != 2) h[gn * 64 + lane] = hv;
    float s = hv, q = hv * hv;
#pragma unroll
    for (int m = 1; m < 64; m <<= 1) {
      s += __shfl_xor(s, m);
      q += __shfl_xor(q, m);
    }
    float mu = s * (1.0f / 64.0f);
    float var = q * (1.0f / 64.0f) - mu * mu;
    float r = rsqrtf(var + LNEPS);
    float f = fmaxf((hv - mu) * r * gnv + bnv, 0.f);
    if (mode == 2) {
      float p = f * linW[(gn & 4095) * 64 + lane];
#pragma unroll
      for (int m = 1; m < 64; m <<= 1) p += __shfl_xor(p, m);
      if (lane == 0) partials[gn] = p;
    } else {
      hin_out[gn * 64 + lane] = f;
    }
  }
}

// ---------- final per-sample reduction ----------
__global__ __launch_bounds__(256) void k_readout2(const float* __restrict__ partials,
                                                  const float* __restrict__ linb,
                                                  float* __restrict__ out) {
  __shared__ float s[256];
  int b = blockIdx.x, t = threadIdx.x;
  float acc = 0.0f;
  for (int i = t; i < 4096; i += 256) acc += partials[b * 4096 + i];
  s[t] = acc;
  __syncthreads();
  for (int d = 128; d > 0; d >>= 1) {
    if (t < d) s[t] += s[t + d];
    __syncthreads();
  }
  if (t == 0) out[b] = s[0] + linb[0];
}

}  // namespace

extern "C" void kernel_launch(void* const* d_in, const int* in_sizes, int n_in,
                              void* d_out, int out_size, void* d_ws, size_t ws_size,
                              hipStream_t stream) {
  const float* x = (const float*)d_in[0];
  const int* ei = (const int*)d_in[1];
  const float* ea = (const float*)d_in[2];
  const float* nW = (const float*)d_in[5];
  const float* nb = (const float*)d_in[6];
  const float* eW = (const float*)d_in[7];
  const float* eb = (const float*)d_in[8];
  const float* W1 = (const float*)d_in[9];
  const float* b1 = (const float*)d_in[10];
  const float* g1 = (const float*)d_in[11];
  const float* bt1 = (const float*)d_in[12];
  const float* W2 = (const float*)d_in[13];
  const float* b2 = (const float*)d_in[14];
  const float* ct = (const float*)d_in[15];
  const float* lng = (const float*)d_in[16];
  const float* lnb = (const float*)d_in[17];
  const float* linW = (const float*)d_in[18];
  const float* linb = (const float*)d_in[19];
  float* out = (float*)d_out;

  const int* src = ei;
  const int* dst = ei + NE;

  // workspace carve
  char* p = (char*)d_ws;
  auto alloc = [&](size_t bytes) {
    char* r = p;
    p += (bytes + 255) & ~size_t(255);
    return r;
  };
  float* h = (float*)alloc(size_t(NN) * 64 * 4);
  float* hin = (float*)alloc(size_t(NN) * 64 * 4);
  float* zbuf = (float*)alloc(size_t(NN) * 64 * 4);
  float* eenc = (float*)alloc(size_t(65536) * 64 * 4);
  unsigned* epack = (unsigned*)alloc(size_t(NE) * 4);
  int* counts = (int*)alloc(size_t(NN) * 4);
  int* offsets = (int*)alloc(size_t(NN + 1) * 4);
  int* blockTot = (int*)alloc(256 * 4);
  int* cursor = (int*)alloc(size_t(NN) * 4);
  float* partials = (float*)alloc(size_t(NN) * 4);

  k_encode<<<16384, 256, 0, stream>>>(x, ea, nW, nb, eW, eb, h, eenc);

  hipMemsetAsync(counts, 0, size_t(NN) * 4, stream);
  k_count<<<NE / 256, 256, 0, stream>>>(dst, counts);
  k_scan1<<<256, 256, 0, stream>>>(counts, offsets, blockTot);
  k_scan2<<<1, 256, 0, stream>>>(blockTot);
  k_scan3<<<256, 256, 0, stream>>>(blockTot, offsets, cursor);
  k_scatter<<<NE / 256, 256, 0, stream>>>(src, dst, cursor, epack);

  for (int l = 0; l < NL; ++l) {
    const float* hi = (l == 0) ? h : hin;
    k_agg<<<NN / 4, 256, 0, stream>>>(hi, eenc, offsets, epack, ct, l, zbuf);
    int mode = (l == 0) ? 0 : (l == NL - 1 ? 2 : 1);
    const float* gnext = (l == NL - 1) ? lng : lng + (l + 1) * 64;
    const float* bnext = (l == NL - 1) ? lnb : lnb + (l + 1) * 64;
    k_mlp<<<NN / 32, 256, 0, stream>>>(zbuf, h, hin,
                                       W1 + l * H2 * 64, b1 + l * H2,
                                       g1 + l * H2, bt1 + l * H2,
                                       W2 + l * 64 * H2, b2 + l * 64,
                                       gnext, bnext, linW, partials, mode);
  }

  k_readout2<<<16, 256, 0, stream>>>(partials, linb, out);
}

// Round 3
// 523.780 us; speedup vs baseline: 1.7145x; 1.4131x over previous
//
#include <hip/hip_runtime.h>

namespace {

typedef __attribute__((ext_vector_type(8))) short bf16x8;
typedef __attribute__((ext_vector_type(4))) float f32x4;

constexpr int NN = 65536;      // nodes
constexpr int NE = 1 << 20;    // edges
constexpr int H2 = 128;        // 2*hidden
constexpr int NL = 4;          // layers
constexpr float GEPS = 1e-7f;
constexpr float LNEPS = 1e-5f;

__device__ inline unsigned short f2bf(float f) {
  unsigned u = __builtin_bit_cast(unsigned, f);
  return (unsigned short)((u + 0x7fffu + ((u >> 16) & 1u)) >> 16);
}
__device__ inline float bf2f(unsigned short b) {
  unsigned u = ((unsigned)b) << 16;
  return __builtin_bit_cast(float, u);
}

// ---------- encoders: h[N,64], eenc[65536,64] ----------
__global__ __launch_bounds__(256) void k_encode(
    const float* __restrict__ x, const float* __restrict__ ea,
    const float* __restrict__ nW, const float* __restrict__ nb,
    const float* __restrict__ eW, const float* __restrict__ eb,
    float* __restrict__ h, float* __restrict__ eenc) {
  int g = blockIdx.x * 256 + threadIdx.x;
  int c = g & 63;
  int i = g >> 6;
  h[g] = x[i] * nW[c] + nb[c];
  eenc[g] = ea[i] * eW[c] + eb[c];
}

// ---------- counting sort by dst ----------
__global__ __launch_bounds__(256) void k_count(const int* __restrict__ dst,
                                               int* __restrict__ counts) {
  int e = blockIdx.x * 256 + threadIdx.x;
  atomicAdd(&counts[dst[e]], 1);
}

__global__ __launch_bounds__(256) void k_scan1(const int* __restrict__ counts,
                                               int* __restrict__ offsets,
                                               int* __restrict__ blockTot) {
  __shared__ int s[256];
  int t = threadIdx.x;
  int g = blockIdx.x * 256 + t;
  int v = counts[g];
  s[t] = v;
  __syncthreads();
  for (int d = 1; d < 256; d <<= 1) {
    int val = (t >= d) ? s[t - d] : 0;
    __syncthreads();
    s[t] += val;
    __syncthreads();
  }
  offsets[g] = s[t] - v;
  if (t == 255) blockTot[blockIdx.x] = s[255];
}

__global__ __launch_bounds__(256) void k_scan2(int* __restrict__ blockTot) {
  __shared__ int s[256];
  int t = threadIdx.x;
  int v = blockTot[t];
  s[t] = v;
  __syncthreads();
  for (int d = 1; d < 256; d <<= 1) {
    int val = (t >= d) ? s[t - d] : 0;
    __syncthreads();
    s[t] += val;
    __syncthreads();
  }
  blockTot[t] = s[t] - v;
}

__global__ __launch_bounds__(256) void k_scan3(const int* __restrict__ blockTot,
                                               int* __restrict__ offsets,
                                               int* __restrict__ cursor) {
  int g = blockIdx.x * 256 + threadIdx.x;
  int v = offsets[g] + blockTot[blockIdx.x];
  offsets[g] = v;
  cursor[g] = v;
  if (g == 0) offsets[NN] = NE;
}

__global__ __launch_bounds__(256) void k_scatter(const int* __restrict__ src,
                                                 const int* __restrict__ dst,
                                                 int* __restrict__ cursor,
                                                 unsigned* __restrict__ epack) {
  int e = blockIdx.x * 256 + threadIdx.x;
  int d = dst[e];
  int pos = atomicAdd(&cursor[d], 1);
  epack[pos] = ((unsigned)src[e] << 16) | (unsigned)(e & 65535);
}

// ---------- per-dst online-softmax aggregation; z = agg + hi ----------
__global__ __launch_bounds__(256) void k_agg(const float* __restrict__ hin,
                                             const float* __restrict__ eenc,
                                             const int* __restrict__ offsets,
                                             const unsigned* __restrict__ epack,
                                             const float* __restrict__ conv_t, int layer,
                                             float* __restrict__ zbuf) {
  int lane = threadIdx.x & 63;
  int d = blockIdx.x * 4 + (threadIdx.x >> 6);
  float t = conv_t[layer];
  int off = __builtin_amdgcn_readfirstlane(offsets[d]);
  int end = __builtin_amdgcn_readfirstlane(offsets[d + 1]);
  float hself = hin[d * 64 + lane];

  float mxA = -INFINITY, denA = 0.f, numA = 0.f;
  float mxB = -INFINITY, denB = 0.f, numB = 0.f;

  auto chunk4 = [&](int k, float& mx, float& den, float& num) {
    unsigned p0 = epack[k], p1 = epack[k + 1], p2 = epack[k + 2], p3 = epack[k + 3];
    float g0 = hin[(p0 >> 16) * 64 + lane] + eenc[(p0 & 65535u) * 64 + lane];
    float g1 = hin[(p1 >> 16) * 64 + lane] + eenc[(p1 & 65535u) * 64 + lane];
    float g2 = hin[(p2 >> 16) * 64 + lane] + eenc[(p2 & 65535u) * 64 + lane];
    float g3 = hin[(p3 >> 16) * 64 + lane] + eenc[(p3 & 65535u) * 64 + lane];
    float m0 = fmaxf(g0, 0.f) + GEPS, m1 = fmaxf(g1, 0.f) + GEPS;
    float m2 = fmaxf(g2, 0.f) + GEPS, m3 = fmaxf(g3, 0.f) + GEPS;
    float l0 = m0 * t, l1 = m1 * t, l2 = m2 * t, l3 = m3 * t;
    float nm = fmaxf(fmaxf(fmaxf(l0, l1), fmaxf(l2, l3)), mx);
    float sc = __expf(mx - nm);
    float e0 = __expf(l0 - nm), e1 = __expf(l1 - nm);
    float e2 = __expf(l2 - nm), e3 = __expf(l3 - nm);
    den = den * sc + ((e0 + e1) + (e2 + e3));
    num = num * sc + ((m0 * e0 + m1 * e1) + (m2 * e2 + m3 * e3));
    mx = nm;
  };

  int k = off;
  for (; k + 8 <= end; k += 8) {
    chunk4(k, mxA, denA, numA);
    chunk4(k + 4, mxB, denB, numB);
  }
  if (k + 4 <= end) { chunk4(k, mxA, denA, numA); k += 4; }
  for (; k < end; ++k) {
    unsigned p = epack[k];
    float g = hin[(p >> 16) * 64 + lane] + eenc[(p & 65535u) * 64 + lane];
    float m = fmaxf(g, 0.f) + GEPS;
    float lg = m * t;
    float nm = fmaxf(mxA, lg);
    float sc = __expf(mxA - nm), ex = __expf(lg - nm);
    denA = denA * sc + ex;
    numA = numA * sc + m * ex;
    mxA = nm;
  }
  float mxm = fmaxf(mxA, mxB);
  float scA = (mxA == mxm) ? 1.f : __expf(mxA - mxm);
  float scB = (mxB == mxm) ? 1.f : __expf(mxB - mxm);
  float den = denA * scA + denB * scB;
  float num = numA * scA + numB * scB;
  float agg = num / fmaxf(den, 1e-16f);
  zbuf[d * 64 + lane] = agg + hself;
}

// ---------- weight prep: split W1/W2 into bf16 hi/lo A-fragments ----------
// A-frag layout (16x16x32): lane holds A[m = lane&15][k = ks*32 + (lane>>4)*8 + j]
// frag array idx: ((fid)*64 + lane)*8 + j; W1: fid = nt*2 + ks; W2: fid = mt*4 + ks
__global__ __launch_bounds__(256) void k_wprep(const float* __restrict__ W1,
                                               const float* __restrict__ W2,
                                               unsigned short* __restrict__ w1hi,
                                               unsigned short* __restrict__ w1lo,
                                               unsigned short* __restrict__ w2hi,
                                               unsigned short* __restrict__ w2lo) {
  int t = blockIdx.x * 256 + threadIdx.x;   // 0..65535
  int which = t >> 15;
  int o = t & 32767;                        // layer*8192 + idx
  int l = o >> 13, idx = o & 8191;
  int fid = idx >> 9, lane = (idx >> 3) & 63, j = idx & 7;
  int lr = lane & 15, lg = lane >> 4;
  if (which == 0) {
    int nt = fid >> 1, ks = fid & 1;
    int m = nt * 16 + lr, k = ks * 32 + lg * 8 + j;
    float v = W1[l * 8192 + m * 64 + k];
    unsigned short hi = f2bf(v);
    w1hi[o] = hi;
    w1lo[o] = f2bf(v - bf2f(hi));
  } else {
    int mt = fid >> 2, ks = fid & 3;
    int m = mt * 16 + lr, k = ks * 32 + lg * 8 + j;
    float v = W2[l * 8192 + m * 128 + k];
    unsigned short hi = f2bf(v);
    w2hi[o] = hi;
    w2lo[o] = f2bf(v - bf2f(hi));
  }
}

// ---------- MFMA node MLP: one wave owns 16 nodes end-to-end ----------
// GEMM1: D1 = W1(A-frag) x Z^T(B-frag) -> C1: col(lane&15)=node, row=c1
// LN128 + relu in-register; repack hi/lo through swizzled LDS ->
// GEMM2: D2 = W2(A-frag) x Y^T(B-frag) -> C2: col=node, row=c2
// epilogue: +b2, residual, next-layer LN/relu (or readout partials)
__global__ __launch_bounds__(256) void k_mlpmm(const float* __restrict__ zbuf,
                                               float* __restrict__ h,
                                               float* __restrict__ hin,
                                               const unsigned short* __restrict__ w1hi,
                                               const unsigned short* __restrict__ w1lo,
                                               const unsigned short* __restrict__ w2hi,
                                               const unsigned short* __restrict__ w2lo,
                                               const float* __restrict__ b1,
                                               const float* __restrict__ g1,
                                               const float* __restrict__ bt1,
                                               const float* __restrict__ b2,
                                               const float* __restrict__ gnx,
                                               const float* __restrict__ bnx,
                                               const float* __restrict__ linW,
                                               float* __restrict__ partials,
                                               int mode) {
  __shared__ unsigned Yb[4][16 * 132];
  int tid = threadIdx.x, wv = tid >> 6, l = tid & 63;
  int lr = l & 15, lg = l >> 4;
  unsigned* Y = Yb[wv];
  int n0 = (blockIdx.x * 4 + wv) * 16;

  // ---- B-frags from z (each lane reads its own node's row; 8 consecutive k)
  bf16x8 zh[2], zl[2];
#pragma unroll
  for (int ks = 0; ks < 2; ++ks) {
    const float* zp = zbuf + (n0 + lr) * 64 + ks * 32 + lg * 8;
    float4 a = *(const float4*)zp, b = *(const float4*)(zp + 4);
    float zv[8] = {a.x, a.y, a.z, a.w, b.x, b.y, b.z, b.w};
    bf16x8 hh, ll;
#pragma unroll
    for (int j = 0; j < 8; ++j) {
      unsigned short hi = f2bf(zv[j]);
      hh[j] = (short)hi;
      ll[j] = (short)f2bf(zv[j] - bf2f(hi));
    }
    zh[ks] = hh;
    zl[ks] = ll;
  }

  // ---- GEMM1 (split bf16: AhBh + AlBh + AhBl)
  f32x4 C1[8];
#pragma unroll
  for (int nt = 0; nt < 8; ++nt) {
    bf16x8 a0h = *(const bf16x8*)(w1hi + ((nt * 2 + 0) * 64 + l) * 8);
    bf16x8 a0l = *(const bf16x8*)(w1lo + ((nt * 2 + 0) * 64 + l) * 8);
    bf16x8 a1h = *(const bf16x8*)(w1hi + ((nt * 2 + 1) * 64 + l) * 8);
    bf16x8 a1l = *(const bf16x8*)(w1lo + ((nt * 2 + 1) * 64 + l) * 8);
    f32x4 c = {0.f, 0.f, 0.f, 0.f};
    c = __builtin_amdgcn_mfma_f32_16x16x32_bf16(a0h, zh[0], c, 0, 0, 0);
    c = __builtin_amdgcn_mfma_f32_16x16x32_bf16(a0l, zh[0], c, 0, 0, 0);
    c = __builtin_amdgcn_mfma_f32_16x16x32_bf16(a0h, zl[0], c, 0, 0, 0);
    c = __builtin_amdgcn_mfma_f32_16x16x32_bf16(a1h, zh[1], c, 0, 0, 0);
    c = __builtin_amdgcn_mfma_f32_16x16x32_bf16(a1l, zh[1], c, 0, 0, 0);
    c = __builtin_amdgcn_mfma_f32_16x16x32_bf16(a1h, zl[1], c, 0, 0, 0);
    C1[nt] = c;
  }

  // ---- +b1, LN over 128 (per node = per lane&15), relu, split, stash to LDS
  float s = 0.f, q = 0.f;
#pragma unroll
  for (int nt = 0; nt < 8; ++nt) {
    float4 bv = *(const float4*)(b1 + nt * 16 + lg * 4);
#pragma unroll
    for (int r = 0; r < 4; ++r) {
      float v = C1[nt][r] + ((const float*)&bv)[r];
      C1[nt][r] = v;
      s += v;
      q += v * v;
    }
  }
  s += __shfl_xor(s, 16); q += __shfl_xor(q, 16);
  s += __shfl_xor(s, 32); q += __shfl_xor(q, 32);
  float mu = s * (1.f / 128.f);
  float rs = rsqrtf(q * (1.f / 128.f) - mu * mu + LNEPS);
#pragma unroll
  for (int nt = 0; nt < 8; ++nt) {
    float4 gv = *(const float4*)(g1 + nt * 16 + lg * 4);
    float4 btv = *(const float4*)(bt1 + nt * 16 + lg * 4);
    unsigned pk[4];
#pragma unroll
    for (int r = 0; r < 4; ++r) {
      float y = fmaxf((C1[nt][r] - mu) * rs * ((const float*)&gv)[r] + ((const float*)&btv)[r], 0.f);
      unsigned short hi = f2bf(y);
      unsigned short lo = f2bf(y - bf2f(hi));
      pk[r] = (unsigned)hi | ((unsigned)lo << 16);
    }
    int idx = lr * 132 + ((nt * 16 + lg * 4) ^ ((lr & 7) << 2));
    *(uint4*)(Y + idx) = make_uint4(pk[0], pk[1], pk[2], pk[3]);
  }

  // ---- read back as GEMM2 B-frags (lane's own node row, 8 consecutive k)
  bf16x8 yh[4], yl[4];
#pragma unroll
  for (int ks = 0; ks < 4; ++ks) {
    bf16x8 hh, ll;
#pragma unroll
    for (int half = 0; half < 2; ++half) {
      int cb = ks * 32 + lg * 8 + half * 4;
      uint4 v = *(const uint4*)(Y + lr * 132 + (cb ^ ((lr & 7) << 2)));
      unsigned dw[4] = {v.x, v.y, v.z, v.w};
#pragma unroll
      for (int j = 0; j < 4; ++j) {
        hh[half * 4 + j] = (short)(dw[j] & 0xffffu);
        ll[half * 4 + j] = (short)(dw[j] >> 16);
      }
    }
    yh[ks] = hh;
    yl[ks] = ll;
  }

  // ---- GEMM2
  f32x4 C2[4];
#pragma unroll
  for (int mt = 0; mt < 4; ++mt) {
    f32x4 c = {0.f, 0.f, 0.f, 0.f};
#pragma unroll
    for (int ks = 0; ks < 4; ++ks) {
      bf16x8 ah = *(const bf16x8*)(w2hi + ((mt * 4 + ks) * 64 + l) * 8);
      bf16x8 al = *(const bf16x8*)(w2lo + ((mt * 4 + ks) * 64 + l) * 8);
      c = __builtin_amdgcn_mfma_f32_16x16x32_bf16(ah, yh[ks], c, 0, 0, 0);
      c = __builtin_amdgcn_mfma_f32_16x16x32_bf16(al, yh[ks], c, 0, 0, 0);
      c = __builtin_amdgcn_mfma_f32_16x16x32_bf16(ah, yl[ks], c, 0, 0, 0);
    }
    C2[mt] = c;
  }

  // ---- epilogue: +b2, residual, LN64(next) + relu -> hin, or readout partials
  int gnode = n0 + lr;
  float s2 = 0.f, q2 = 0.f;
#pragma unroll
  for (int mt = 0; mt < 4; ++mt) {
    float4 b2v = *(const float4*)(b2 + mt * 16 + lg * 4);
    float4 hr = {0.f, 0.f, 0.f, 0.f};
    if (mode != 0) hr = *(const float4*)(h + gnode * 64 + mt * 16 + lg * 4);
    float4 hv;
#pragma unroll
    for (int r = 0; r < 4; ++r) {
      float o = C2[mt][r] + ((const float*)&b2v)[r];
      float v = (mode == 0) ? o : ((const float*)&hr)[r] + o;
      ((float*)&hv)[r] = v;
      s2 += v;
      q2 += v * v;
      C2[mt][r] = v;
    }
    if (mode != 2) *(float4*)(h + gnode * 64 + mt * 16 + lg * 4) = hv;
  }
  s2 += __shfl_xor(s2, 16); q2 += __shfl_xor(q2, 16);
  s2 += __shfl_xor(s2, 32); q2 += __shfl_xor(q2, 32);
  float mu2 = s2 * (1.f / 64.f);
  float rs2 = rsqrtf(q2 * (1.f / 64.f) - mu2 * mu2 + LNEPS);
  if (mode != 2) {
#pragma unroll
    for (int mt = 0; mt < 4; ++mt) {
      float4 gv = *(const float4*)(gnx + mt * 16 + lg * 4);
      float4 bv = *(const float4*)(bnx + mt * 16 + lg * 4);
      float4 fo;
#pragma unroll
      for (int r = 0; r < 4; ++r)
        ((float*)&fo)[r] = fmaxf((C2[mt][r] - mu2) * rs2 * ((const float*)&gv)[r] + ((const float*)&bv)[r], 0.f);
      *(float4*)(hin + gnode * 64 + mt * 16 + lg * 4) = fo;
    }
  } else {
    float p = 0.f;
#pragma unroll
    for (int mt = 0; mt < 4; ++mt) {
      float4 gv = *(const float4*)(gnx + mt * 16 + lg * 4);
      float4 bv = *(const float4*)(bnx + mt * 16 + lg * 4);
      float4 lw = *(const float4*)(linW + (gnode & 4095) * 64 + mt * 16 + lg * 4);
#pragma unroll
      for (int r = 0; r < 4; ++r) {
        float f = fmaxf((C2[mt][r] - mu2) * rs2 * ((const float*)&gv)[r] + ((const float*)&bv)[r], 0.f);
        p += f * ((const float*)&lw)[r];
      }
    }
    p += __shfl_xor(p, 16);
    p += __shfl_xor(p, 32);
    if (lg == 0) partials[gnode] = p;
  }
}

// ---------- final per-sample reduction ----------
__global__ __launch_bounds__(256) void k_readout2(const float* __restrict__ partials,
                                                  const float* __restrict__ linb,
                                                  float* __restrict__ out) {
  __shared__ float s[256];
  int b = blockIdx.x, t = threadIdx.x;
  float acc = 0.0f;
  for (int i = t; i < 4096; i += 256) acc += partials[b * 4096 + i];
  s[t] = acc;
  __syncthreads();
  for (int d = 128; d > 0; d >>= 1) {
    if (t < d) s[t] += s[t + d];
    __syncthreads();
  }
  if (t == 0) out[b] = s[0] + linb[0];
}

}  // namespace

extern "C" void kernel_launch(void* const* d_in, const int* in_sizes, int n_in,
                              void* d_out, int out_size, void* d_ws, size_t ws_size,
                              hipStream_t stream) {
  const float* x = (const float*)d_in[0];
  const int* ei = (const int*)d_in[1];
  const float* ea = (const float*)d_in[2];
  const float* nW = (const float*)d_in[5];
  const float* nb = (const float*)d_in[6];
  const float* eW = (const float*)d_in[7];
  const float* eb = (const float*)d_in[8];
  const float* W1 = (const float*)d_in[9];
  const float* b1 = (const float*)d_in[10];
  const float* g1 = (const float*)d_in[11];
  const float* bt1 = (const float*)d_in[12];
  const float* W2 = (const float*)d_in[13];
  const float* b2 = (const float*)d_in[14];
  const float* ct = (const float*)d_in[15];
  const float* lng = (const float*)d_in[16];
  const float* lnb = (const float*)d_in[17];
  const float* linW = (const float*)d_in[18];
  const float* linb = (const float*)d_in[19];
  float* out = (float*)d_out;

  const int* src = ei;
  const int* dst = ei + NE;

  char* p = (char*)d_ws;
  auto alloc = [&](size_t bytes) {
    char* r = p;
    p += (bytes + 255) & ~size_t(255);
    return r;
  };
  float* h = (float*)alloc(size_t(NN) * 64 * 4);
  float* hin = (float*)alloc(size_t(NN) * 64 * 4);
  float* zbuf = (float*)alloc(size_t(NN) * 64 * 4);
  float* eenc = (float*)alloc(size_t(65536) * 64 * 4);
  unsigned* epack = (unsigned*)alloc(size_t(NE) * 4);
  int* counts = (int*)alloc(size_t(NN) * 4);
  int* offsets = (int*)alloc(size_t(NN + 1) * 4);
  int* blockTot = (int*)alloc(256 * 4);
  int* cursor = (int*)alloc(size_t(NN) * 4);
  float* partials = (float*)alloc(size_t(NN) * 4);
  unsigned short* w1hi = (unsigned short*)alloc(4 * 8192 * 2);
  unsigned short* w1lo = (unsigned short*)alloc(4 * 8192 * 2);
  unsigned short* w2hi = (unsigned short*)alloc(4 * 8192 * 2);
  unsigned short* w2lo = (unsigned short*)alloc(4 * 8192 * 2);

  k_encode<<<16384, 256, 0, stream>>>(x, ea, nW, nb, eW, eb, h, eenc);
  k_wprep<<<256, 256, 0, stream>>>(W1, W2, w1hi, w1lo, w2hi, w2lo);

  hipMemsetAsync(counts, 0, size_t(NN) * 4, stream);
  k_count<<<NE / 256, 256, 0, stream>>>(dst, counts);
  k_scan1<<<256, 256, 0, stream>>>(counts, offsets, blockTot);
  k_scan2<<<1, 256, 0, stream>>>(blockTot);
  k_scan3<<<256, 256, 0, stream>>>(blockTot, offsets, cursor);
  k_scatter<<<NE / 256, 256, 0, stream>>>(src, dst, cursor, epack);

  for (int l = 0; l < NL; ++l) {
    const float* hi = (l == 0) ? h : hin;
    k_agg<<<NN / 4, 256, 0, stream>>>(hi, eenc, offsets, epack, ct, l, zbuf);
    int mode = (l == 0) ? 0 : (l == NL - 1 ? 2 : 1);
    const float* gnext = (l == NL - 1) ? lng : lng + (l + 1) * 64;
    const float* bnext = (l == NL - 1) ? lnb : lnb + (l + 1) * 64;
    k_mlpmm<<<NN / 64, 256, 0, stream>>>(zbuf, h, hin,
                                         w1hi + l * 8192, w1lo + l * 8192,
                                         w2hi + l * 8192, w2lo + l * 8192,
                                         b1 + l * H2, g1 + l * H2, bt1 + l * H2,
                                         b2 + l * 64, gnext, bnext,
                                         linW, partials, mode);
  }

  k_readout2<<<16, 256, 0, stream>>>(partials, linb, out);
}

// Round 4
// 422.159 us; speedup vs baseline: 2.1272x; 1.2407x over previous
//
#include <hip/hip_runtime.h>

namespace {

typedef __attribute__((ext_vector_type(8))) short bf16x8;
typedef __attribute__((ext_vector_type(4))) float f32x4;

constexpr int NN = 65536;      // nodes
constexpr int NE = 1 << 20;    // edges
constexpr int H2 = 128;        // 2*hidden
constexpr int NL = 4;          // layers
constexpr float GEPS = 1e-7f;
constexpr float LNEPS = 1e-5f;

__device__ inline unsigned f2bf(float f) {
  unsigned u = __builtin_bit_cast(unsigned, f);
  return (u + 0x7fffu + ((u >> 16) & 1u)) >> 16;
}
__device__ inline float bf2f(unsigned b) {
  unsigned u = b << 16;
  return __builtin_bit_cast(float, u);
}

// ---------- binned counting sort (256 buckets by dst>>8) ----------
__global__ __launch_bounds__(256) void kA0(const int* __restrict__ dst,
                                           int* __restrict__ bcnt) {
  __shared__ int h[256];
  int t = threadIdx.x;
  h[t] = 0;
  __syncthreads();
  int bs = blockIdx.x * 4096;
#pragma unroll 4
  for (int i = 0; i < 16; ++i) {
    int d = dst[bs + i * 256 + t];
    atomicAdd(&h[d >> 8], 1);
  }
  __syncthreads();
  atomicAdd(&bcnt[t], h[t]);
}

__global__ __launch_bounds__(256) void kScanB(const int* __restrict__ bcnt,
                                              int* __restrict__ bbase,
                                              int* __restrict__ cursorA) {
  __shared__ int s[256];
  int t = threadIdx.x;
  int v = bcnt[t];
  s[t] = v;
  __syncthreads();
  for (int dd = 1; dd < 256; dd <<= 1) {
    int val = (t >= dd) ? s[t - dd] : 0;
    __syncthreads();
    s[t] += val;
    __syncthreads();
  }
  int ex = s[t] - v;
  bbase[t] = ex;
  cursorA[t] = ex;
  if (t == 255) bbase[256] = NE;
}

// bin edges into coarse buckets; record = {src | (dst&255)<<16, ea_bits}
__global__ __launch_bounds__(256) void kA1(const int* __restrict__ src,
                                           const int* __restrict__ dst,
                                           const float* __restrict__ ea0,
                                           int* __restrict__ cursorA,
                                           uint2* __restrict__ binned) {
  __shared__ int h[256], lcur[256], base[256];
  int t = threadIdx.x;
  h[t] = 0;
  lcur[t] = 0;
  __syncthreads();
  int bs = blockIdx.x * 4096;
#pragma unroll 4
  for (int i = 0; i < 16; ++i) {
    int d = dst[bs + i * 256 + t];
    atomicAdd(&h[d >> 8], 1);
  }
  __syncthreads();
  base[t] = atomicAdd(&cursorA[t], h[t]);
  __syncthreads();
  for (int i = 0; i < 16; ++i) {
    int e = bs + i * 256 + t;
    int d = dst[e];
    int s = src[e];
    float a = ea0[e & 65535];
    int b = d >> 8;
    int k = atomicAdd(&lcur[b], 1);
    uint2 r;
    r.x = (unsigned)s | ((unsigned)(d & 255) << 16);
    r.y = __builtin_bit_cast(unsigned, a);
    binned[base[b] + k] = r;
  }
}

// exact sort within bucket; emits per-dst offsets and final records {src, ea}
__global__ __launch_bounds__(256) void kB(const uint2* __restrict__ binned,
                                          const int* __restrict__ bbase,
                                          uint2* __restrict__ recs,
                                          int* __restrict__ offsets) {
  __shared__ int h[256], sc[256], ex[256], lcur[256];
  int t = threadIdx.x;
  int b = blockIdx.x;
  int s0 = bbase[b], s1 = bbase[b + 1], n = s1 - s0;
  h[t] = 0;
  lcur[t] = 0;
  __syncthreads();
  for (int i = t; i < n; i += 256) atomicAdd(&h[(binned[s0 + i].x >> 16) & 255], 1);
  __syncthreads();
  sc[t] = h[t];
  __syncthreads();
  for (int dd = 1; dd < 256; dd <<= 1) {
    int val = (t >= dd) ? sc[t - dd] : 0;
    __syncthreads();
    sc[t] += val;
    __syncthreads();
  }
  ex[t] = sc[t] - h[t];
  offsets[b * 256 + t] = s0 + ex[t];
  if (b == 0 && t == 0) offsets[NN] = NE;
  __syncthreads();
  for (int i = t; i < n; i += 256) {
    uint2 r = binned[s0 + i];
    int d8 = (r.x >> 16) & 255;
    int k = atomicAdd(&lcur[d8], 1);
    uint2 o;
    o.x = r.x & 0xffffu;
    o.y = r.y;
    recs[s0 + ex[d8] + k] = o;
  }
}

// ---------- per-dst online-softmax aggregation; z = agg + hself ----------
// edge feature computed on the fly: e_c = ea*eW[c]+eb[c]
// layer0: h rows are rank-1: h[s][c] = x[s]*nW[c]+nb[c]  (scalar broadcast gather)
// layers>=1: gather bf16 hin rows; self term from f32 hin
__global__ __launch_bounds__(256) void k_agg(const unsigned short* __restrict__ hinb,
                                             const float* __restrict__ hinf,
                                             const float* __restrict__ x,
                                             const float* __restrict__ nW,
                                             const float* __restrict__ nb,
                                             const float* __restrict__ eW,
                                             const float* __restrict__ eb,
                                             const int* __restrict__ offsets,
                                             const uint2* __restrict__ recs,
                                             const float* __restrict__ conv_t, int layer,
                                             int l0,
                                             float* __restrict__ zbuf) {
  int lane = threadIdx.x & 63;
  int d = blockIdx.x * 4 + (threadIdx.x >> 6);
  float t = conv_t[layer];
  float eWl = eW[lane], ebl = eb[lane];
  float nWl = nW[lane], nbl = nb[lane];
  int off = __builtin_amdgcn_readfirstlane(offsets[d]);
  int end = __builtin_amdgcn_readfirstlane(offsets[d + 1]);
  float hself = l0 ? (x[d] * nWl + nbl) : hinf[d * 64 + lane];

  float mxA = -INFINITY, denA = 0.f, numA = 0.f;
  float mxB = -INFINITY, denB = 0.f, numB = 0.f;

  auto edgeval = [&](int k) -> float {
    uint2 r = recs[k];
    int s = __builtin_amdgcn_readfirstlane((int)r.x);
    float a = __builtin_bit_cast(float, __builtin_amdgcn_readfirstlane((int)r.y));
    float ec = a * eWl + ebl;
    float hs = l0 ? (x[s] * nWl + nbl) : bf2f(hinb[s * 64 + lane]);
    return hs + ec;
  };

  auto chunk4 = [&](int k, float& mx, float& den, float& num) {
    float g0 = edgeval(k), g1 = edgeval(k + 1), g2 = edgeval(k + 2), g3 = edgeval(k + 3);
    float m0 = fmaxf(g0, 0.f) + GEPS, m1 = fmaxf(g1, 0.f) + GEPS;
    float m2 = fmaxf(g2, 0.f) + GEPS, m3 = fmaxf(g3, 0.f) + GEPS;
    float l0_ = m0 * t, l1_ = m1 * t, l2_ = m2 * t, l3_ = m3 * t;
    float nm = fmaxf(fmaxf(fmaxf(l0_, l1_), fmaxf(l2_, l3_)), mx);
    float sc = __expf(mx - nm);
    float e0 = __expf(l0_ - nm), e1 = __expf(l1_ - nm);
    float e2 = __expf(l2_ - nm), e3 = __expf(l3_ - nm);
    den = den * sc + ((e0 + e1) + (e2 + e3));
    num = num * sc + ((m0 * e0 + m1 * e1) + (m2 * e2 + m3 * e3));
    mx = nm;
  };

  int k = off;
  for (; k + 8 <= end; k += 8) {
    chunk4(k, mxA, denA, numA);
    chunk4(k + 4, mxB, denB, numB);
  }
  if (k + 4 <= end) { chunk4(k, mxA, denA, numA); k += 4; }
  for (; k < end; ++k) {
    float g = edgeval(k);
    float m = fmaxf(g, 0.f) + GEPS;
    float lg = m * t;
    float nm = fmaxf(mxA, lg);
    float sc = __expf(mxA - nm), exx = __expf(lg - nm);
    denA = denA * sc + exx;
    numA = numA * sc + m * exx;
    mxA = nm;
  }
  float mxm = fmaxf(mxA, mxB);
  float scA = (mxA == mxm) ? 1.f : __expf(mxA - mxm);
  float scB = (mxB == mxm) ? 1.f : __expf(mxB - mxm);
  float den = denA * scA + denB * scB;
  float num = numA * scA + numB * scB;
  float agg = num / fmaxf(den, 1e-16f);
  zbuf[d * 64 + lane] = agg + hself;
}

// ---------- weight prep: split W1/W2 into bf16 hi/lo A-fragments ----------
__global__ __launch_bounds__(256) void k_wprep(const float* __restrict__ W1,
                                               const float* __restrict__ W2,
                                               unsigned short* __restrict__ w1hi,
                                               unsigned short* __restrict__ w1lo,
                                               unsigned short* __restrict__ w2hi,
                                               unsigned short* __restrict__ w2lo) {
  int t = blockIdx.x * 256 + threadIdx.x;   // 0..65535
  int which = t >> 15;
  int o = t & 32767;                        // layer*8192 + idx
  int l = o >> 13, idx = o & 8191;
  int fid = idx >> 9, lane = (idx >> 3) & 63, j = idx & 7;
  int lr = lane & 15, lg = lane >> 4;
  if (which == 0) {
    int nt = fid >> 1, ks = fid & 1;
    int m = nt * 16 + lr, k = ks * 32 + lg * 8 + j;
    float v = W1[l * 8192 + m * 64 + k];
    unsigned hi = f2bf(v);
    w1hi[o] = (unsigned short)hi;
    w1lo[o] = (unsigned short)f2bf(v - bf2f(hi));
  } else {
    int mt = fid >> 2, ks = fid & 3;
    int m = mt * 16 + lr, k = ks * 32 + lg * 8 + j;
    float v = W2[l * 8192 + m * 128 + k];
    unsigned hi = f2bf(v);
    w2hi[o] = (unsigned short)hi;
    w2lo[o] = (unsigned short)f2bf(v - bf2f(hi));
  }
}

// ---------- MFMA node MLP: one wave owns 16 nodes end-to-end ----------
__global__ __launch_bounds__(256) void k_mlpmm(const float* __restrict__ zbuf,
                                               float* __restrict__ h,
                                               float* __restrict__ hinf,
                                               unsigned short* __restrict__ hinb,
                                               const unsigned short* __restrict__ w1hi,
                                               const unsigned short* __restrict__ w1lo,
                                               const unsigned short* __restrict__ w2hi,
                                               const unsigned short* __restrict__ w2lo,
                                               const float* __restrict__ b1,
                                               const float* __restrict__ g1,
                                               const float* __restrict__ bt1,
                                               const float* __restrict__ b2,
                                               const float* __restrict__ gnx,
                                               const float* __restrict__ bnx,
                                               const float* __restrict__ linW,
                                               float* __restrict__ partials,
                                               int mode) {
  __shared__ unsigned Yb[4][16 * 132];
  int tid = threadIdx.x, wv = tid >> 6, l = tid & 63;
  int lr = l & 15, lg = l >> 4;
  unsigned* Y = Yb[wv];
  int n0 = (blockIdx.x * 4 + wv) * 16;

  // ---- B-frags from z
  bf16x8 zh[2], zl[2];
#pragma unroll
  for (int ks = 0; ks < 2; ++ks) {
    const float* zp = zbuf + (n0 + lr) * 64 + ks * 32 + lg * 8;
    float4 a = *(const float4*)zp, b = *(const float4*)(zp + 4);
    float zv[8] = {a.x, a.y, a.z, a.w, b.x, b.y, b.z, b.w};
    bf16x8 hh, ll;
#pragma unroll
    for (int j = 0; j < 8; ++j) {
      unsigned hi = f2bf(zv[j]);
      hh[j] = (short)hi;
      ll[j] = (short)f2bf(zv[j] - bf2f(hi));
    }
    zh[ks] = hh;
    zl[ks] = ll;
  }

  // ---- GEMM1 (split bf16: AhBh + AlBh + AhBl)
  f32x4 C1[8];
#pragma unroll
  for (int nt = 0; nt < 8; ++nt) {
    bf16x8 a0h = *(const bf16x8*)(w1hi + ((nt * 2 + 0) * 64 + l) * 8);
    bf16x8 a0l = *(const bf16x8*)(w1lo + ((nt * 2 + 0) * 64 + l) * 8);
    bf16x8 a1h = *(const bf16x8*)(w1hi + ((nt * 2 + 1) * 64 + l) * 8);
    bf16x8 a1l = *(const bf16x8*)(w1lo + ((nt * 2 + 1) * 64 + l) * 8);
    f32x4 c = {0.f, 0.f, 0.f, 0.f};
    c = __builtin_amdgcn_mfma_f32_16x16x32_bf16(a0h, zh[0], c, 0, 0, 0);
    c = __builtin_amdgcn_mfma_f32_16x16x32_bf16(a0l, zh[0], c, 0, 0, 0);
    c = __builtin_amdgcn_mfma_f32_16x16x32_bf16(a0h, zl[0], c, 0, 0, 0);
    c = __builtin_amdgcn_mfma_f32_16x16x32_bf16(a1h, zh[1], c, 0, 0, 0);
    c = __builtin_amdgcn_mfma_f32_16x16x32_bf16(a1l, zh[1], c, 0, 0, 0);
    c = __builtin_amdgcn_mfma_f32_16x16x32_bf16(a1h, zl[1], c, 0, 0, 0);
    C1[nt] = c;
  }

  // ---- +b1, LN over 128, relu, split, stash to LDS
  float s = 0.f, q = 0.f;
#pragma unroll
  for (int nt = 0; nt < 8; ++nt) {
    float4 bv = *(const float4*)(b1 + nt * 16 + lg * 4);
#pragma unroll
    for (int r = 0; r < 4; ++r) {
      float v = C1[nt][r] + ((const float*)&bv)[r];
      C1[nt][r] = v;
      s += v;
      q += v * v;
    }
  }
  s += __shfl_xor(s, 16); q += __shfl_xor(q, 16);
  s += __shfl_xor(s, 32); q += __shfl_xor(q, 32);
  float mu = s * (1.f / 128.f);
  float rs = rsqrtf(q * (1.f / 128.f) - mu * mu + LNEPS);
#pragma unroll
  for (int nt = 0; nt < 8; ++nt) {
    float4 gv = *(const float4*)(g1 + nt * 16 + lg * 4);
    float4 btv = *(const float4*)(bt1 + nt * 16 + lg * 4);
    unsigned pk[4];
#pragma unroll
    for (int r = 0; r < 4; ++r) {
      float y = fmaxf((C1[nt][r] - mu) * rs * ((const float*)&gv)[r] + ((const float*)&btv)[r], 0.f);
      unsigned hi = f2bf(y);
      unsigned lo = f2bf(y - bf2f(hi));
      pk[r] = hi | (lo << 16);
    }
    int idx = lr * 132 + ((nt * 16 + lg * 4) ^ ((lr & 7) << 2));
    *(uint4*)(Y + idx) = make_uint4(pk[0], pk[1], pk[2], pk[3]);
  }

  // ---- read back as GEMM2 B-frags
  bf16x8 yh[4], yl[4];
#pragma unroll
  for (int ks = 0; ks < 4; ++ks) {
    bf16x8 hh, ll;
#pragma unroll
    for (int half = 0; half < 2; ++half) {
      int cb = ks * 32 + lg * 8 + half * 4;
      uint4 v = *(const uint4*)(Y + lr * 132 + (cb ^ ((lr & 7) << 2)));
      unsigned dw[4] = {v.x, v.y, v.z, v.w};
#pragma unroll
      for (int j = 0; j < 4; ++j) {
        hh[half * 4 + j] = (short)(dw[j] & 0xffffu);
        ll[half * 4 + j] = (short)(dw[j] >> 16);
      }
    }
    yh[ks] = hh;
    yl[ks] = ll;
  }

  // ---- GEMM2
  f32x4 C2[4];
#pragma unroll
  for (int mt = 0; mt < 4; ++mt) {
    f32x4 c = {0.f, 0.f, 0.f, 0.f};
#pragma unroll
    for (int ks = 0; ks < 4; ++ks) {
      bf16x8 ah = *(const bf16x8*)(w2hi + ((mt * 4 + ks) * 64 + l) * 8);
      bf16x8 al = *(const bf16x8*)(w2lo + ((mt * 4 + ks) * 64 + l) * 8);
      c = __builtin_amdgcn_mfma_f32_16x16x32_bf16(ah, yh[ks], c, 0, 0, 0);
      c = __builtin_amdgcn_mfma_f32_16x16x32_bf16(al, yh[ks], c, 0, 0, 0);
      c = __builtin_amdgcn_mfma_f32_16x16x32_bf16(ah, yl[ks], c, 0, 0, 0);
    }
    C2[mt] = c;
  }

  // ---- epilogue
  int gnode = n0 + lr;
  float s2 = 0.f, q2 = 0.f;
#pragma unroll
  for (int mt = 0; mt < 4; ++mt) {
    float4 b2v = *(const float4*)(b2 + mt * 16 + lg * 4);
    float4 hr = {0.f, 0.f, 0.f, 0.f};
    if (mode != 0) hr = *(const float4*)(h + gnode * 64 + mt * 16 + lg * 4);
    float4 hv;
#pragma unroll
    for (int r = 0; r < 4; ++r) {
      float o = C2[mt][r] + ((const float*)&b2v)[r];
      float v = (mode == 0) ? o : ((const float*)&hr)[r] + o;
      ((float*)&hv)[r] = v;
      s2 += v;
      q2 += v * v;
      C2[mt][r] = v;
    }
    if (mode != 2) *(float4*)(h + gnode * 64 + mt * 16 + lg * 4) = hv;
  }
  s2 += __shfl_xor(s2, 16); q2 += __shfl_xor(q2, 16);
  s2 += __shfl_xor(s2, 32); q2 += __shfl_xor(q2, 32);
  float mu2 = s2 * (1.f / 64.f);
  float rs2 = rsqrtf(q2 * (1.f / 64.f) - mu2 * mu2 + LNEPS);
  if (mode != 2) {
#pragma unroll
    for (int mt = 0; mt < 4; ++mt) {
      float4 gv = *(const float4*)(gnx + mt * 16 + lg * 4);
      float4 bv = *(const float4*)(bnx + mt * 16 + lg * 4);
      float4 fo;
#pragma unroll
      for (int r = 0; r < 4; ++r)
        ((float*)&fo)[r] = fmaxf((C2[mt][r] - mu2) * rs2 * ((const float*)&gv)[r] + ((const float*)&bv)[r], 0.f);
      *(float4*)(hinf + gnode * 64 + mt * 16 + lg * 4) = fo;
      uint2 pb;
      pb.x = f2bf(fo.x) | (f2bf(fo.y) << 16);
      pb.y = f2bf(fo.z) | (f2bf(fo.w) << 16);
      *(uint2*)(hinb + gnode * 64 + mt * 16 + lg * 4) = pb;
    }
  } else {
    float p = 0.f;
#pragma unroll
    for (int mt = 0; mt < 4; ++mt) {
      float4 gv = *(const float4*)(gnx + mt * 16 + lg * 4);
      float4 bv = *(const float4*)(bnx + mt * 16 + lg * 4);
      float4 lw = *(const float4*)(linW + (gnode & 4095) * 64 + mt * 16 + lg * 4);
#pragma unroll
      for (int r = 0; r < 4; ++r) {
        float f = fmaxf((C2[mt][r] - mu2) * rs2 * ((const float*)&gv)[r] + ((const float*)&bv)[r], 0.f);
        p += f * ((const float*)&lw)[r];
      }
    }
    p += __shfl_xor(p, 16);
    p += __shfl_xor(p, 32);
    if (lg == 0) partials[gnode] = p;
  }
}

// ---------- final per-sample reduction ----------
__global__ __launch_bounds__(256) void k_readout2(const float* __restrict__ partials,
                                                  const float* __restrict__ linb,
                                                  float* __restrict__ out) {
  __shared__ float s[256];
  int b = blockIdx.x, t = threadIdx.x;
  float acc = 0.0f;
  for (int i = t; i < 4096; i += 256) acc += partials[b * 4096 + i];
  s[t] = acc;
  __syncthreads();
  for (int d = 128; d > 0; d >>= 1) {
    if (t < d) s[t] += s[t + d];
    __syncthreads();
  }
  if (t == 0) out[b] = s[0] + linb[0];
}

}  // namespace

extern "C" void kernel_launch(void* const* d_in, const int* in_sizes, int n_in,
                              void* d_out, int out_size, void* d_ws, size_t ws_size,
                              hipStream_t stream) {
  const float* x = (const float*)d_in[0];
  const int* ei = (const int*)d_in[1];
  const float* ea = (const float*)d_in[2];
  const float* nW = (const float*)d_in[5];
  const float* nb = (const float*)d_in[6];
  const float* eW = (const float*)d_in[7];
  const float* eb = (const float*)d_in[8];
  const float* W1 = (const float*)d_in[9];
  const float* b1 = (const float*)d_in[10];
  const float* g1 = (const float*)d_in[11];
  const float* bt1 = (const float*)d_in[12];
  const float* W2 = (const float*)d_in[13];
  const float* b2 = (const float*)d_in[14];
  const float* ct = (const float*)d_in[15];
  const float* lng = (const float*)d_in[16];
  const float* lnb = (const float*)d_in[17];
  const float* linW = (const float*)d_in[18];
  const float* linb = (const float*)d_in[19];
  float* out = (float*)d_out;

  const int* src = ei;
  const int* dst = ei + NE;

  char* p = (char*)d_ws;
  auto alloc = [&](size_t bytes) {
    char* r = p;
    p += (bytes + 255) & ~size_t(255);
    return r;
  };
  float* h = (float*)alloc(size_t(NN) * 64 * 4);
  float* hinf = (float*)alloc(size_t(NN) * 64 * 4);
  unsigned short* hinb = (unsigned short*)alloc(size_t(NN) * 64 * 2);
  float* zbuf = (float*)alloc(size_t(NN) * 64 * 4);
  uint2* binned = (uint2*)alloc(size_t(NE) * 8);
  uint2* recs = (uint2*)alloc(size_t(NE) * 8);
  int* offsets = (int*)alloc(size_t(NN + 1) * 4);
  int* bcnt = (int*)alloc(256 * 4);
  int* bbase = (int*)alloc(257 * 4);
  int* cursorA = (int*)alloc(256 * 4);
  float* partials = (float*)alloc(size_t(NN) * 4);
  unsigned short* w1hi = (unsigned short*)alloc(4 * 8192 * 2);
  unsigned short* w1lo = (unsigned short*)alloc(4 * 8192 * 2);
  unsigned short* w2hi = (unsigned short*)alloc(4 * 8192 * 2);
  unsigned short* w2lo = (unsigned short*)alloc(4 * 8192 * 2);

  k_wprep<<<256, 256, 0, stream>>>(W1, W2, w1hi, w1lo, w2hi, w2lo);

  hipMemsetAsync(bcnt, 0, 256 * 4, stream);
  kA0<<<256, 256, 0, stream>>>(dst, bcnt);
  kScanB<<<1, 256, 0, stream>>>(bcnt, bbase, cursorA);
  kA1<<<256, 256, 0, stream>>>(src, dst, ea, cursorA, binned);
  kB<<<256, 256, 0, stream>>>(binned, bbase, recs, offsets);

  for (int l = 0; l < NL; ++l) {
    k_agg<<<NN / 4, 256, 0, stream>>>(hinb, hinf, x, nW, nb, eW, eb,
                                      offsets, recs, ct, l, (l == 0) ? 1 : 0, zbuf);
    int mode = (l == 0) ? 0 : (l == NL - 1 ? 2 : 1);
    const float* gnext = (l == NL - 1) ? lng : lng + (l + 1) * 64;
    const float* bnext = (l == NL - 1) ? lnb : lnb + (l + 1) * 64;
    k_mlpmm<<<NN / 64, 256, 0, stream>>>(zbuf, h, hinf, hinb,
                                         w1hi + l * 8192, w1lo + l * 8192,
                                         w2hi + l * 8192, w2lo + l * 8192,
                                         b1 + l * H2, g1 + l * H2, bt1 + l * H2,
                                         b2 + l * 64, gnext, bnext,
                                         linW, partials, mode);
  }

  k_readout2<<<16, 256, 0, stream>>>(partials, linb, out);
}